// Round 6
// baseline (1481.672 us; speedup 1.0000x reference)
//
#include <hip/hip_runtime.h>

#define T_STEPS 1024
#define B_SEQ   4096

typedef float v2f __attribute__((ext_vector_type(2)));
typedef float v4f __attribute__((ext_vector_type(4)));

template<int N>
__device__ __forceinline__ float rorf(float x) {  // row_ror:N over 16-lane rows
    return __int_as_float(__builtin_amdgcn_mov_dpp(__float_as_int(x), 0x120 + N, 0xF, 0xF, false));
}
template<int N>
__device__ __forceinline__ v2f ror2(v2f x) { v2f r; r.x = rorf<N>(x.x); r.y = rorf<N>(x.y); return r; }

__device__ __forceinline__ float swz16(float x) {  // lane ^= 16
    return __int_as_float(__builtin_amdgcn_ds_swizzle(__float_as_int(x), 0x401F));
}

__device__ __forceinline__ v4f pkfma4(v4f a, v4f b, v4f c) { return __builtin_elementwise_fma(a, b, c); }
__device__ __forceinline__ v2f pkfma2(v2f a, v2f b, v2f c) { return __builtin_elementwise_fma(a, b, c); }

// Runtime dtype sniff (insurance; rounds 1-3 proved inputs are f32).
__device__ __forceinline__ bool sniff_is_bf16(const void* p) {
    unsigned short h = ((const unsigned short*)p)[threadIdx.x & 63];
    union { unsigned u; float f; } c; c.u = ((unsigned)h) << 16;
    float f = fabsf(c.f);
    bool bad = !(f <= 1e4f) || (f != 0.0f && f < 1e-10f);
    return __ballot(bad) == 0ULL;
}
__device__ __forceinline__ float ldf(const void* p, long long i, bool isbf) {
    if (isbf) {
        unsigned short h = ((const unsigned short*)p)[i];
        union { unsigned u; float f; } c; c.u = ((unsigned)h) << 16;
        return c.f;
    }
    return ((const float*)p)[i];
}

// 64-thread single-wave blocks; 4 sequences per block (ILP-2 per 32-lane half).
// lane = half*32 + net*16 + j ; half handles seqs sA = blk*4+half (slot A)
// and sB = sA+2 (slot B), statically interleaved for latency hiding.
__global__ __launch_bounds__(64, 1) void reac_rk4_kernel(
    const void* __restrict__ u_,     const void* __restrict__ xz0_,
    const void* __restrict__ r1_W0_, const void* __restrict__ r1_b0_,
    const void* __restrict__ r1_W1_, const void* __restrict__ r1_b1_,
    const void* __restrict__ r1_W2_, const void* __restrict__ r1_b2_,
    const void* __restrict__ r2_W0_, const void* __restrict__ r2_b0_,
    const void* __restrict__ r2_W1_, const void* __restrict__ r2_b1_,
    const void* __restrict__ r2_W2_, const void* __restrict__ r2_b2_,
    const void* __restrict__ ymean_, const void* __restrict__ ystd_,
    const void* __restrict__ umean_, const void* __restrict__ ustd_,
    float* __restrict__ out)
{
    // h1 staging: slot A at [0,64), slot B at [64,128). Single wave ->
    // per-wave in-order DS semantics, no barriers needed.
    __shared__ __align__(16) float shm[128];

    const int tid  = threadIdx.x;
    const int j    = tid & 15;
    const int net  = (tid >> 4) & 1;
    const int half = tid >> 5;
    const long long sA = (long long)blockIdx.x * 4 + half;
    const long long sB = sA + 2;

    const bool vW = sniff_is_bf16(r1_W1_);
    const bool vU = sniff_is_bf16(u_);
    const bool vX = sniff_is_bf16(xz0_);

    // ---- per-lane weights (shared by both slots) ----
    float w0a, w0b, b0;
    if (net) { w0a = ldf(r2_W0_, j, vW); w0b = ldf(r2_W0_, 16 + j, vW); b0 = ldf(r2_b0_, j, vW); }
    else     { w0a = ldf(r1_W0_, j, vW); w0b = 0.0f;                    b0 = ldf(r1_b0_, j, vW); }
    const void* W1 = net ? r2_W1_ : r1_W1_;
    v4f w4[4];
    #pragma unroll
    for (int q = 0; q < 4; ++q)
        #pragma unroll
        for (int i = 0; i < 4; ++i)
            w4[q][i] = ldf(W1, (4 * q + i) * 16 + j, vW);
    const float b1v = ldf(net ? r2_b1_ : r1_b1_, j, vW);

    const float Camean = ldf(ymean_, 0, vW), Cbmean = ldf(ymean_, 1, vW);
    const float Castd  = ldf(ystd_,  0, vW), Cbstd  = ldf(ystd_,  1, vW);
    const float um     = ldf(umean_, 0, vW), us     = ldf(ustd_,  0, vW);
    const float invCastd = 1.0f / Castd, invCbstd = 1.0f / Cbstd;
    const float ostd = net ? Cbstd : Castd;
    const float w2s  = ldf(net ? r2_W2_ : r1_W2_, j, vW) * ostd;
    const float b2s  = ldf(net ? r2_b2_ : r1_b2_, 0, vW) * ostd;

    // ---- packed constants ----
    const v2f L2E2   = { 2.88539008177793f, 2.88539008177793f };
    const v2f ONE2   = { 1.0f, 1.0f };
    const v2f MTWO2  = { -2.0f, -2.0f };
    const v2f W0A2   = { w0a, w0a }, W0B2 = { w0b, w0b }, B02 = { b0, b0 };
    const v2f W2S2   = { w2s, w2s }, B2S2 = { b2s, b2s };
    const v2f MTHREE2= { -3.0f, -3.0f };
    const v2f MP1_2  = { -0.1f, -0.1f };
    const v2f CBSTD2 = { Cbstd, Cbstd }, CBMEAN2 = { Cbmean, Cbmean }, ICBSTD2 = { invCbstd, invCbstd };
    const v2f US2    = { us, us }, UM2 = { um, um }, P1_2 = { 0.1f, 0.1f };
    const v4f STD4   = { Castd, Castd, Cbstd, Cbstd };
    const v4f MEAN4  = { Camean, Camean, Cbmean, Cbmean };
    const v4f ISTD4  = { invCastd, invCastd, invCbstd, invCbstd };
    const v4f MP1_4  = { -0.1f, -0.1f, -0.1f, -0.1f };
    const v4f HALF4  = { 0.5f, 0.5f, 0.5f, 0.5f };
    const v2f HALF2  = { 0.5f, 0.5f };
    const v4f TWO4   = { 2.0f, 2.0f, 2.0f, 2.0f };
    const v2f TWO2   = { 2.0f, 2.0f };
    const v4f SIXTH4 = { 1.f/6.f, 1.f/6.f, 1.f/6.f, 1.f/6.f };
    const v2f SIXTH2 = { 1.f/6.f, 1.f/6.f };

    // ---- state: X = {CaA, CaB, CbA, CbB}, Xc = {CcA, CcB} ----
    v4f X;  X.x = ldf(xz0_, sA * 3 + 0, vX); X.y = ldf(xz0_, sB * 3 + 0, vX);
            X.z = ldf(xz0_, sA * 3 + 1, vX); X.w = ldf(xz0_, sB * 3 + 1, vX);
    v2f Xc; Xc.x = ldf(xz0_, sA * 3 + 2, vX); Xc.y = ldf(xz0_, sB * 3 + 2, vX);

    // ---- output lanes: c=0,1 -> yseq; c=2,3,4 -> xseq ----
    const int  c      = tid & 31;
    const bool active = (c < 5);
    const long long XOFF = (long long)B_SEQ * T_STEPS * 2;
    float *spA, *spB;
    int sstr;
    if (c < 2) { spA = out + sA * (T_STEPS * 2) + c;          spB = out + sB * (T_STEPS * 2) + c;          sstr = 2; }
    else       { spA = out + XOFF + sA * (T_STEPS * 3) + (c - 2); spB = out + XOFF + sB * (T_STEPS * 3) + (c - 2); sstr = 3; }
    const bool selA = (c == 0) | (c == 2);
    const bool selB = (c == 1) | (c == 3);

    const long long ubA = sA * T_STEPS, ubB = sB * T_STEPS;
    v2f ut; ut.x = ldf(u_, ubA, vU); ut.y = ldf(u_, ubB, vU);

    // packed tanh: 2 scalar exp2 + 2 scalar rcp, rest pk
    auto tanh2 = [&](v2f x) -> v2f {
        v2f m = x * L2E2;
        v2f e; e.x = __builtin_amdgcn_exp2f(m.x); e.y = __builtin_amdgcn_exp2f(m.y);
        v2f s = e + ONE2;
        v2f r; r.x = __builtin_amdgcn_rcpf(s.x); r.y = __builtin_amdgcn_rcpf(s.y);
        return pkfma2(MTWO2, r, ONE2);
    };

    const v4f* gA = (const v4f*)(shm + (tid & 48));
    const v4f* gB = (const v4f*)(shm + 64 + (tid & 48));

    auto fxu2 = [&](v4f x, v2f xc, v2f fCaf2, v4f& K, v2f& Kc) {
        // layer 1 (both slots packed)
        v2f xa; xa.x = x.x; xa.y = x.y;          // Ca slots
        v2f xb; xb.x = x.z; xb.y = x.w;          // Cb slots
        v2f A0  = net ? xb : xa;
        v2f pre = pkfma2(W0A2, A0, pkfma2(W0B2, xc, B02));
        v2f h1  = tanh2(pre);
        // stage + broadcast gather (slot A then B regions)
        shm[tid] = h1.x; shm[tid + 64] = h1.y;   // -> ds_write2_b32
        v4f qA0 = gA[0], qA1 = gA[1], qA2 = gA[2], qA3 = gA[3];
        v4f qB0 = gB[0], qB1 = gB[1], qB2 = gB[2], qB3 = gB[3];
        // layer 2
        v4f aA = { b1v, 0.0f, 0.0f, 0.0f }, aB = { b1v, 0.0f, 0.0f, 0.0f };
        aA = pkfma4(qA0, w4[0], aA); aB = pkfma4(qB0, w4[0], aB);
        aA = pkfma4(qA1, w4[1], aA); aB = pkfma4(qB1, w4[1], aB);
        aA = pkfma4(qA2, w4[2], aA); aB = pkfma4(qB2, w4[2], aB);
        aA = pkfma4(qA3, w4[3], aA); aB = pkfma4(qB3, w4[3], aB);
        v2f dot; dot.x = (aA.x + aA.y) + (aA.z + aA.w);
                 dot.y = (aB.x + aB.y) + (aB.z + aB.w);
        v2f h2 = tanh2(dot);
        // layer 3: packed DPP rotate-reduce over the 16-lane net group
        v2f p = h2 * W2S2;
        p = p + ror2<8>(p); p = p + ror2<4>(p); p = p + ror2<2>(p); p = p + ror2<1>(p);
        v2f ov = p + B2S2;
        v2f other; other.x = swz16(ov.x); other.y = swz16(ov.y);
        v2f r1v = net ? other : ov;              // = r1 * Castd (per slot)
        v2f r2v = net ? ov : other;              // = r2 * Cbstd
        // physics (packed)
        v4f Cp  = pkfma4(x, STD4, MEAN4);
        v2f Ccp = pkfma2(xc, CBSTD2, CBMEAN2);
        v2f tA  = fCaf2 - r1v;                   // dCa rhs
        v2f tB  = pkfma2(MTHREE2, r2v, r1v);     // dCb rhs
        v4f rhs; rhs.x = tA.x; rhs.y = tA.y; rhs.z = tB.x; rhs.w = tB.y;
        K  = pkfma4(MP1_4, Cp, rhs) * ISTD4;
        Kc = pkfma2(MP1_2, Ccp, r2v) * ICBSTD2;
    };

    for (int t = 0; t < T_STEPS; ++t) {
        float vA = selA ? X.x : (selB ? X.z : Xc.x);
        float vB = selA ? X.y : (selB ? X.w : Xc.y);
        if (active) { *spA = vA; *spB = vB; spA += sstr; spB += sstr; }
        if (t == T_STEPS - 1) break;

        v2f utn; utn.x = ldf(u_, ubA + t + 1, vU); utn.y = ldf(u_, ubB + t + 1, vU);
        v2f fCaf2 = P1_2 * pkfma2(ut, US2, UM2);

        v4f K1, K2, K3, K4; v2f K1c, K2c, K3c, K4c;
        fxu2(X, Xc, fCaf2, K1, K1c);
        fxu2(pkfma4(HALF4, K1, X), pkfma2(HALF2, K1c, Xc), fCaf2, K2, K2c);
        fxu2(pkfma4(HALF4, K2, X), pkfma2(HALF2, K2c, Xc), fCaf2, K3, K3c);
        fxu2(X + K3, Xc + K3c, fCaf2, K4, K4c);

        v4f S  = pkfma4(TWO4, K2 + K3, K1) + K4;
        v2f Sc = pkfma2(TWO2, K2c + K3c, K1c) + K4c;
        X  = pkfma4(SIXTH4, S, X);
        Xc = pkfma2(SIXTH2, Sc, Xc);
        ut = utn;
    }
}

extern "C" void kernel_launch(void* const* d_in, const int* in_sizes, int n_in,
                              void* d_out, int out_size, void* d_ws, size_t ws_size,
                              hipStream_t stream) {
    (void)in_sizes; (void)n_in; (void)out_size; (void)d_ws; (void)ws_size;
    dim3 grid(B_SEQ / 4);   // 1024 single-wave blocks, 4 seqs each
    dim3 block(64);
    reac_rk4_kernel<<<grid, block, 0, stream>>>(
        d_in[0],  d_in[1],
        d_in[2],  d_in[3],  d_in[4],  d_in[5],  d_in[6],  d_in[7],
        d_in[8],  d_in[9],  d_in[10], d_in[11], d_in[12], d_in[13],
        d_in[14], d_in[15], d_in[16], d_in[17],
        (float*)d_out);
}